// Round 5
// baseline (215.992 us; speedup 1.0000x reference)
//
#include <hip/hip_runtime.h>

#define LN_EPS 1e-5f

typedef float v4f __attribute__((ext_vector_type(4)));

constexpr int BLOCK = 512;            // 8 waves
constexpr int RPT   = 8;              // rows per thread
constexpr int RPB   = BLOCK * RPT;    // 4096 rows per block

__global__ __launch_bounds__(BLOCK) void ln_linear_softmax_kernel(
    const v4f*   __restrict__ x,     // [n] rows of 4 floats
    const float* __restrict__ W,     // [4,3] row-major
    const float* __restrict__ gamma, // [4]
    const float* __restrict__ beta,  // [4]
    v4f*         __restrict__ out4,  // out viewed as float4 (n*3/4 elements)
    int n)
{
    __shared__ float lds[RPB * 3];    // 48 KB -> 3 blocks/CU, 24 waves/CU

    const int  tid  = threadIdx.x;
    const long base = (long)blockIdx.x * RPB;
    const bool full = (base + RPB <= (long)n);

    const v4f g = *(const v4f*)gamma;
    const v4f b = *(const v4f*)beta;
    const v4f* W4 = (const v4f*)W;
    const v4f w0 = W4[0]; // W00 W01 W02 W10
    const v4f w1 = W4[1]; // W11 W12 W20 W21
    const v4f w2 = W4[2]; // W22 W30 W31 W32

    if (full) {
        // Hot path: 8 unguarded back-to-back NT loads per lane — long
        // contiguous read burst (8 KB per wave), overhead amortized over
        // 2x the bytes of the previous version.
        v4f v[RPT];
        #pragma unroll
        for (int k = 0; k < RPT; ++k)
            v[k] = __builtin_nontemporal_load(&x[base + tid + k * BLOCK]);

        #pragma unroll
        for (int k = 0; k < RPT; ++k) {
            const int rl = tid + k * BLOCK;
            v4f q = v[k];

            float mu = (q.x + q.y + q.z + q.w) * 0.25f;
            float dx = q.x - mu, dy = q.y - mu, dz = q.z - mu, dw = q.w - mu;
            float var = (dx*dx + dy*dy + dz*dz + dw*dw) * 0.25f;
            float rs  = rsqrtf(var + LN_EPS);

            float h0 = dx * rs * g.x + b.x;
            float h1 = dy * rs * g.y + b.y;
            float h2 = dz * rs * g.z + b.z;
            float h3 = dw * rs * g.w + b.w;

            float l0 = h0*w0.x + h1*w0.w + h2*w1.z + h3*w2.y;
            float l1 = h0*w0.y + h1*w1.x + h2*w1.w + h3*w2.z;
            float l2 = h0*w0.z + h1*w1.y + h2*w2.x + h3*w2.w;

            float m   = fmaxf(l0, fmaxf(l1, l2));
            float e0  = __expf(l0 - m);
            float e1  = __expf(l1 - m);
            float e2  = __expf(l2 - m);
            float inv = 1.0f / (e0 + e1 + e2);

            // dword stride 3 -> exactly 2 lanes/bank (free)
            lds[rl*3 + 0] = e0 * inv;
            lds[rl*3 + 1] = e1 * inv;
            lds[rl*3 + 2] = e2 * inv;
        }

        __syncthreads();

        // Cooperative packed store: RPB*3/4 = 3072 float4s per block,
        // 6 iterations, fully coalesced, unguarded.
        const v4f* lds4  = (const v4f*)lds;
        const long obase = (long)blockIdx.x * (RPB * 3 / 4);
        #pragma unroll
        for (int k = 0; k < 6; ++k) {
            __builtin_nontemporal_store(lds4[tid + k * BLOCK],
                                        &out4[obase + tid + k * BLOCK]);
        }
    } else {
        // Tail block (never hit for the bench shape): per-row scalar path.
        float* out = (float*)out4;
        for (int k = 0; k < RPT; ++k) {
            const long row = base + tid + (long)k * BLOCK;
            if (row < n) {
                v4f q = __builtin_nontemporal_load(&x[row]);

                float mu = (q.x + q.y + q.z + q.w) * 0.25f;
                float dx = q.x - mu, dy = q.y - mu, dz = q.z - mu, dw = q.w - mu;
                float var = (dx*dx + dy*dy + dz*dz + dw*dw) * 0.25f;
                float rs  = rsqrtf(var + LN_EPS);

                float h0 = dx * rs * g.x + b.x;
                float h1 = dy * rs * g.y + b.y;
                float h2 = dz * rs * g.z + b.z;
                float h3 = dw * rs * g.w + b.w;

                float l0 = h0*w0.x + h1*w0.w + h2*w1.z + h3*w2.y;
                float l1 = h0*w0.y + h1*w1.x + h2*w1.w + h3*w2.z;
                float l2 = h0*w0.z + h1*w1.y + h2*w2.x + h3*w2.w;

                float m   = fmaxf(l0, fmaxf(l1, l2));
                float e0  = __expf(l0 - m);
                float e1  = __expf(l1 - m);
                float e2  = __expf(l2 - m);
                float inv = 1.0f / (e0 + e1 + e2);

                out[row*3 + 0] = e0 * inv;
                out[row*3 + 1] = e1 * inv;
                out[row*3 + 2] = e2 * inv;
            }
        }
    }
}

extern "C" void kernel_launch(void* const* d_in, const int* in_sizes, int n_in,
                              void* d_out, int out_size, void* d_ws, size_t ws_size,
                              hipStream_t stream) {
    const float* x     = (const float*)d_in[0];
    const float* W     = (const float*)d_in[1];
    const float* gamma = (const float*)d_in[2];
    const float* beta  = (const float*)d_in[3];
    v4f* out4 = (v4f*)d_out;

    int n = in_sizes[0] / 4;                 // number of rows (8,388,608)
    int grid = (n + RPB - 1) / RPB;          // 2048 blocks
    ln_linear_softmax_kernel<<<grid, BLOCK, 0, stream>>>(
        (const v4f*)x, W, gamma, beta, out4, n);
}

// Round 7
// 214.527 us; speedup vs baseline: 1.0068x; 1.0068x over previous
//
#include <hip/hip_runtime.h>

#define LN_EPS 1e-5f

typedef float v4f __attribute__((ext_vector_type(4)));

constexpr int BLOCK = 512;            // 8 waves
constexpr int RPT   = 4;              // rows per thread
constexpr int RPB   = BLOCK * RPT;    // 2048 rows per block

__global__ __launch_bounds__(BLOCK) void ln_linear_softmax_kernel(
    const v4f*   __restrict__ x,     // [n] rows of 4 floats
    const float* __restrict__ W,     // [4,3] row-major
    const float* __restrict__ gamma, // [4]
    const float* __restrict__ beta,  // [4]
    v4f*         __restrict__ out4,  // out viewed as float4 (n*3/4 elements)
    int n)
{
    __shared__ float lds[RPB * 3];    // 24 KB -> 4 blocks/CU, 32 waves/CU

    const int  tid  = threadIdx.x;
    const long base = (long)blockIdx.x * RPB;
    const bool full = (base + RPB <= (long)n);

    const v4f g = *(const v4f*)gamma;
    const v4f b = *(const v4f*)beta;
    const v4f* W4 = (const v4f*)W;
    const v4f w0 = W4[0]; // W00 W01 W02 W10
    const v4f w1 = W4[1]; // W11 W12 W20 W21
    const v4f w2 = W4[2]; // W22 W30 W31 W32

    if (full) {
        // Hot path: unguarded back-to-back NT loads (evict-first: stream
        // past the poison-fill's L2 writeback drain — R0/R2 A/B win).
        v4f v[RPT];
        #pragma unroll
        for (int k = 0; k < RPT; ++k)
            v[k] = __builtin_nontemporal_load(&x[base + tid + k * BLOCK]);

        #pragma unroll
        for (int k = 0; k < RPT; ++k) {
            const int rl = tid + k * BLOCK;
            v4f q = v[k];

            float mu = (q.x + q.y + q.z + q.w) * 0.25f;
            float dx = q.x - mu, dy = q.y - mu, dz = q.z - mu, dw = q.w - mu;
            float var = (dx*dx + dy*dy + dz*dz + dw*dw) * 0.25f;
            float rs  = rsqrtf(var + LN_EPS);

            float h0 = dx * rs * g.x + b.x;
            float h1 = dy * rs * g.y + b.y;
            float h2 = dz * rs * g.z + b.z;
            float h3 = dw * rs * g.w + b.w;

            float l0 = h0*w0.x + h1*w0.w + h2*w1.z + h3*w2.y;
            float l1 = h0*w0.y + h1*w1.x + h2*w1.w + h3*w2.z;
            float l2 = h0*w0.z + h1*w1.y + h2*w2.x + h3*w2.w;

            float m   = fmaxf(l0, fmaxf(l1, l2));
            float e0  = __expf(l0 - m);
            float e1  = __expf(l1 - m);
            float e2  = __expf(l2 - m);
            float inv = 1.0f / (e0 + e1 + e2);

            // dword stride 3 -> exactly 2 lanes/bank (free)
            lds[rl*3 + 0] = e0 * inv;
            lds[rl*3 + 1] = e1 * inv;
            lds[rl*3 + 2] = e2 * inv;
        }

        __syncthreads();

        // Cooperative packed store: 1536 float4s per block, coalesced.
        // A/B this round: REGULAR (cached, write-back) stores — let L2
        // aggregate full lines like fillBufferAligned does at 6.8 TB/s,
        // instead of nt streaming stores.
        const v4f* lds4  = (const v4f*)lds;
        const long obase = (long)blockIdx.x * (RPB * 3 / 4);
        #pragma unroll
        for (int k = 0; k < 3; ++k) {
            out4[obase + tid + k * BLOCK] = lds4[tid + k * BLOCK];
        }
    } else {
        // Tail block (never hit for the bench shape): per-row scalar path.
        float* out = (float*)out4;
        for (int k = 0; k < RPT; ++k) {
            const long row = base + tid + (long)k * BLOCK;
            if (row < n) {
                v4f q = __builtin_nontemporal_load(&x[row]);

                float mu = (q.x + q.y + q.z + q.w) * 0.25f;
                float dx = q.x - mu, dy = q.y - mu, dz = q.z - mu, dw = q.w - mu;
                float var = (dx*dx + dy*dy + dz*dz + dw*dw) * 0.25f;
                float rs  = rsqrtf(var + LN_EPS);

                float h0 = dx * rs * g.x + b.x;
                float h1 = dy * rs * g.y + b.y;
                float h2 = dz * rs * g.z + b.z;
                float h3 = dw * rs * g.w + b.w;

                float l0 = h0*w0.x + h1*w0.w + h2*w1.z + h3*w2.y;
                float l1 = h0*w0.y + h1*w1.x + h2*w1.w + h3*w2.z;
                float l2 = h0*w0.z + h1*w1.y + h2*w2.x + h3*w2.w;

                float m   = fmaxf(l0, fmaxf(l1, l2));
                float e0  = __expf(l0 - m);
                float e1  = __expf(l1 - m);
                float e2  = __expf(l2 - m);
                float inv = 1.0f / (e0 + e1 + e2);

                out[row*3 + 0] = e0 * inv;
                out[row*3 + 1] = e1 * inv;
                out[row*3 + 2] = e2 * inv;
            }
        }
    }
}

extern "C" void kernel_launch(void* const* d_in, const int* in_sizes, int n_in,
                              void* d_out, int out_size, void* d_ws, size_t ws_size,
                              hipStream_t stream) {
    const float* x     = (const float*)d_in[0];
    const float* W     = (const float*)d_in[1];
    const float* gamma = (const float*)d_in[2];
    const float* beta  = (const float*)d_in[3];
    v4f* out4 = (v4f*)d_out;

    int n = in_sizes[0] / 4;                 // number of rows (8,388,608)
    int grid = (n + RPB - 1) / RPB;          // 4096 blocks
    ln_linear_softmax_kernel<<<grid, BLOCK, 0, stream>>>(
        (const v4f*)x, W, gamma, beta, out4, n);
}

// Round 8
// 211.089 us; speedup vs baseline: 1.0232x; 1.0163x over previous
//
#include <hip/hip_runtime.h>

#define LN_EPS 1e-5f

typedef float v4f __attribute__((ext_vector_type(4)));

constexpr int BLOCK = 512;            // 8 waves
constexpr int RPT   = 4;              // rows per thread
constexpr int RPB   = BLOCK * RPT;    // 2048 rows per block

__global__ __launch_bounds__(BLOCK) void ln_linear_softmax_kernel(
    const v4f*   __restrict__ x,     // [n] rows of 4 floats
    const float* __restrict__ W,     // [4,3] row-major
    const float* __restrict__ gamma, // [4]
    const float* __restrict__ beta,  // [4]
    float*       __restrict__ out,   // [n,3] flat
    int n)
{
    const int  tid  = threadIdx.x;
    const long base = (long)blockIdx.x * RPB;
    const bool full = (base + RPB <= (long)n);

    const v4f g = *(const v4f*)gamma;
    const v4f b = *(const v4f*)beta;
    const v4f* W4 = (const v4f*)W;
    const v4f w0 = W4[0]; // W00 W01 W02 W10
    const v4f w1 = W4[1]; // W11 W12 W20 W21
    const v4f w2 = W4[2]; // W22 W30 W31 W32

    if (full) {
        // Unguarded back-to-back NT loads (evict-first — confirmed win R0/R2).
        v4f v[RPT];
        #pragma unroll
        for (int k = 0; k < RPT; ++k)
            v[k] = __builtin_nontemporal_load(&x[base + tid + k * BLOCK]);

        // Direct strided stores — NO LDS, NO barrier. Per row, 3 NT dword
        // stores at stride-3; within a wave the 3 instructions together
        // fully cover each 768 B output span back-to-back, and CDNA L2
        // keeps per-byte dirty masks (no RFO) so lines merge to full-line
        // HBM writes. Stores issue per-wave right after compute — earliest
        // possible, maximal R/W overlap, no block-wide sync.
        #pragma unroll
        for (int k = 0; k < RPT; ++k) {
            const long row = base + tid + (long)k * BLOCK;
            v4f q = v[k];

            float mu = (q.x + q.y + q.z + q.w) * 0.25f;
            float dx = q.x - mu, dy = q.y - mu, dz = q.z - mu, dw = q.w - mu;
            float var = (dx*dx + dy*dy + dz*dz + dw*dw) * 0.25f;
            float rs  = rsqrtf(var + LN_EPS);

            float h0 = dx * rs * g.x + b.x;
            float h1 = dy * rs * g.y + b.y;
            float h2 = dz * rs * g.z + b.z;
            float h3 = dw * rs * g.w + b.w;

            float l0 = h0*w0.x + h1*w0.w + h2*w1.z + h3*w2.y;
            float l1 = h0*w0.y + h1*w1.x + h2*w1.w + h3*w2.z;
            float l2 = h0*w0.z + h1*w1.y + h2*w2.x + h3*w2.w;

            float m   = fmaxf(l0, fmaxf(l1, l2));
            float e0  = __expf(l0 - m);
            float e1  = __expf(l1 - m);
            float e2  = __expf(l2 - m);
            float inv = 1.0f / (e0 + e1 + e2);

            __builtin_nontemporal_store(e0 * inv, &out[row*3 + 0]);
            __builtin_nontemporal_store(e1 * inv, &out[row*3 + 1]);
            __builtin_nontemporal_store(e2 * inv, &out[row*3 + 2]);
        }
    } else {
        // Tail block (never hit for the bench shape): per-row scalar path.
        for (int k = 0; k < RPT; ++k) {
            const long row = base + tid + (long)k * BLOCK;
            if (row < n) {
                v4f q = __builtin_nontemporal_load(&x[row]);

                float mu = (q.x + q.y + q.z + q.w) * 0.25f;
                float dx = q.x - mu, dy = q.y - mu, dz = q.z - mu, dw = q.w - mu;
                float var = (dx*dx + dy*dy + dz*dz + dw*dw) * 0.25f;
                float rs  = rsqrtf(var + LN_EPS);

                float h0 = dx * rs * g.x + b.x;
                float h1 = dy * rs * g.y + b.y;
                float h2 = dz * rs * g.z + b.z;
                float h3 = dw * rs * g.w + b.w;

                float l0 = h0*w0.x + h1*w0.w + h2*w1.z + h3*w2.y;
                float l1 = h0*w0.y + h1*w1.x + h2*w1.w + h3*w2.z;
                float l2 = h0*w0.z + h1*w1.y + h2*w2.x + h3*w2.w;

                float m   = fmaxf(l0, fmaxf(l1, l2));
                float e0  = __expf(l0 - m);
                float e1  = __expf(l1 - m);
                float e2  = __expf(l2 - m);
                float inv = 1.0f / (e0 + e1 + e2);

                out[row*3 + 0] = e0 * inv;
                out[row*3 + 1] = e1 * inv;
                out[row*3 + 2] = e2 * inv;
            }
        }
    }
}

extern "C" void kernel_launch(void* const* d_in, const int* in_sizes, int n_in,
                              void* d_out, int out_size, void* d_ws, size_t ws_size,
                              hipStream_t stream) {
    const float* x     = (const float*)d_in[0];
    const float* W     = (const float*)d_in[1];
    const float* gamma = (const float*)d_in[2];
    const float* beta  = (const float*)d_in[3];
    float* out = (float*)d_out;

    int n = in_sizes[0] / 4;                 // number of rows (8,388,608)
    int grid = (n + RPB - 1) / RPB;          // 4096 blocks
    ln_linear_softmax_kernel<<<grid, BLOCK, 0, stream>>>(
        (const v4f*)x, W, gamma, beta, out, n);
}